// Round 1
// baseline (11206.989 us; speedup 1.0000x reference)
//
#include <hip/hip_runtime.h>
#include <hip/hip_bf16.h>
#include <stdint.h>

// Problem constants
#define BB 128
#define TT 1024
#define II 256
#define HH 256
#define G4 1024   // 4*H

#define Y1_DEPTH 16  // y1 inter-layer ring depth (power of 2)

typedef __attribute__((ext_vector_type(8))) short short8;
typedef __attribute__((ext_vector_type(4))) float float4v;

__device__ __forceinline__ unsigned short f2bf(float f) {
  union { float f; unsigned u; } v; v.f = f;
  unsigned u = v.u + 0x7FFFu + ((v.u >> 16) & 1u);  // RNE; inputs finite
  return (unsigned short)(u >> 16);
}

__device__ __forceinline__ float sigm(float x) { return 1.f / (1.f + __expf(-x)); }
__device__ __forceinline__ float tanhfast(float x) { return 2.f / (1.f + __expf(-2.f * x)) - 1.f; }

__device__ __forceinline__ void spin_wait(int* p, int want) {
  int it = 0;
  while (__hip_atomic_load(p, __ATOMIC_RELAXED, __HIP_MEMORY_SCOPE_AGENT) < want) {
    __builtin_amdgcn_s_sleep(1);
    if (++it > (1 << 24)) break;  // safety: never hang the harness
  }
}

// 64 persistent blocks: [layer(2)] x [batch-group(4), 32 rows each] x [gate-slice(8), 32 j each].
// Each block: LDS-resident bf16 weight slice [128 rows x (256 ih | 256 hh)],
// per-step GEMM M=32,N=128,K=512 via mfma_f32_16x16x32_bf16, c-state in registers,
// h exchanged via global ring (depth 2) with device-scope flag sync,
// y1 layer1->layer2 via depth-16 ring with producer/consumer flags.
__global__ __launch_bounds__(256, 1) void vlstm(
    const float* __restrict__ x, const float* __restrict__ W_ih,
    const float* __restrict__ W_hh, const float* __restrict__ b_ih,
    const float* __restrict__ b_hh, const float* __restrict__ masks,
    float* __restrict__ out, int* __restrict__ flags,
    unsigned short* __restrict__ hstate, unsigned short* __restrict__ y1ring)
{
  const int tid = threadIdx.x;
  const int bid = blockIdx.x;
  const int layer = bid >> 5;          // 0..1
  const int bg = (bid >> 3) & 3;       // batch group 0..3 (32 rows)
  const int gs = bid & 7;              // gate j-slice 0..7 (32 j)
  const int bbase = bg * 32, jbase = gs * 32;

  // LDS: weights 128x520 bf16 (pad 512->520 kills 16-way bank conflict on b128 reads),
  // gates scratch 32x136 fp32 (136 keeps float4 rows 16B-aligned), bias 128 fp32.
  __shared__ unsigned short Wlds[128][520];   // 133,120 B
  __shared__ float gsh[32][136];              //  17,408 B
  __shared__ float bias_sh[128];              //     512 B  -> total 151,040 <= 160K

  // ---- one-time: stage weight slice (rows n = jl*4+q -> global row q*H + jbase + jl) ----
  const float* Wih_l = W_ih + (size_t)layer * G4 * II;
  const float* Whh_l = W_hh + (size_t)layer * G4 * HH;
  for (int e = tid; e < 128 * 512; e += 256) {
    int n = e >> 9, c = e & 511;
    int r = (n & 3) * HH + jbase + (n >> 2);
    float w = (c < 256) ? Wih_l[(size_t)r * II + c] : Whh_l[(size_t)r * HH + (c - 256)];
    Wlds[n][c] = f2bf(w);
  }
  if (tid < 128) {
    int r = (tid & 3) * HH + jbase + (tid >> 2);
    bias_sh[tid] = b_ih[layer * G4 + r] + b_hh[layer * G4 + r];
  }

  // ---- per-thread elementwise state: 4 (m,jl) items, c fp32 + 3 masks in regs ----
  float cst[4], m_out[4], m_h[4], m_c[4];
  #pragma unroll
  for (int r = 0; r < 4; ++r) {
    int idx = r * 256 + tid;
    int m = idx >> 5, jl = idx & 31;
    int b = bbase + m, j = jbase + jl;
    const float* mk = masks + (size_t)layer * 3 * BB * HH;
    m_out[r] = mk[(size_t)0 * BB * HH + (size_t)b * HH + j];
    m_h[r]   = mk[(size_t)1 * BB * HH + (size_t)b * HH + j];
    m_c[r]   = mk[(size_t)2 * BB * HH + (size_t)b * HH + j];
    cst[r] = 0.f;
  }
  __syncthreads();

  const int wv = tid >> 6;       // wave 0..3 -> owns 32 gate-cols
  const int lane = tid & 63;
  const int lr = lane & 15;      // A-row / B-col within 16x16 tile
  const int lg = lane >> 4;      // k-group (8 consecutive k)

  int* fown = flags + layer * 4 * TT + bg * TT;  // this (layer,bg)'s per-step flags
  int* fin  = flags + bg * TT;                   // layer-0 flags (layer-1 input ready)
  int* fl2  = flags + 4 * TT + bg * TT;          // layer-1 flags (ring space for layer-0)
  unsigned short* hs_l = hstate + (size_t)layer * 2 * BB * HH;

  for (int t = 0; t < TT; ++t) {
    // ---- waits: siblings done t-1; layer2: y1_t ready; layer1: ring slot free ----
    if (tid == 0) {
      if (t > 0) spin_wait(fown + (t - 1), 8);
      if (layer == 1) spin_wait(fin + t, 8);
      else if (t >= Y1_DEPTH) spin_wait(fl2 + (t - Y1_DEPTH), 8);
    }
    __syncthreads();
    __builtin_amdgcn_fence(__ATOMIC_ACQUIRE, "agent");

    const unsigned short* hread = hs_l + (size_t)((t + 1) & 1) * BB * HH;  // t=0 reads zeroed slot 1

    // ---- A fragments: K-concat [x_t | h_{t-1}] (layer0) or [y1_t | h_{t-1}] (layer1) ----
    short8 afrag[2][16];
    #pragma unroll
    for (int mt = 0; mt < 2; ++mt) {
      const int b = bbase + mt * 16 + lr;
      if (layer == 0) {
        const float* xp = x + ((size_t)b * TT + t) * II + lg * 8;
        #pragma unroll
        for (int kt = 0; kt < 8; ++kt) {
          float4v v0 = *(const float4v*)(xp + kt * 32);
          float4v v1 = *(const float4v*)(xp + kt * 32 + 4);
          short8 s;
          s[0] = (short)f2bf(v0[0]); s[1] = (short)f2bf(v0[1]);
          s[2] = (short)f2bf(v0[2]); s[3] = (short)f2bf(v0[3]);
          s[4] = (short)f2bf(v1[0]); s[5] = (short)f2bf(v1[1]);
          s[6] = (short)f2bf(v1[2]); s[7] = (short)f2bf(v1[3]);
          afrag[mt][kt] = s;
        }
      } else {
        const unsigned short* yp =
            y1ring + ((size_t)(t & (Y1_DEPTH - 1)) * BB + b) * HH + lg * 8;
        #pragma unroll
        for (int kt = 0; kt < 8; ++kt)
          afrag[mt][kt] = *(const short8*)(yp + kt * 32);
      }
      const unsigned short* hp = hread + (size_t)b * HH + lg * 8;
      #pragma unroll
      for (int kt = 0; kt < 8; ++kt)
        afrag[mt][8 + kt] = *(const short8*)(hp + kt * 32);
    }

    // ---- MFMA: gates[m][n] = sum_k A[m][k] * W[n][k], per wave N=32 ----
    float4v acc[2][2] = {};
    #pragma unroll
    for (int kt = 0; kt < 16; ++kt) {
      #pragma unroll
      for (int nt = 0; nt < 2; ++nt) {
        short8 bfrag = *(const short8*)&Wlds[wv * 32 + nt * 16 + lr][kt * 32 + lg * 8];
        #pragma unroll
        for (int mt = 0; mt < 2; ++mt)
          acc[mt][nt] = __builtin_amdgcn_mfma_f32_16x16x32_bf16(
              afrag[mt][kt], bfrag, acc[mt][nt], 0, 0, 0);
      }
    }

    // ---- gates -> LDS (C/D layout: col=lane&15, row=(lane>>4)*4+reg) ----
    #pragma unroll
    for (int mt = 0; mt < 2; ++mt)
      #pragma unroll
      for (int nt = 0; nt < 2; ++nt)
        #pragma unroll
        for (int rg = 0; rg < 4; ++rg)
          gsh[mt * 16 + lg * 4 + rg][wv * 32 + nt * 16 + lr] = acc[mt][nt][rg];
    __syncthreads();

    // ---- elementwise LSTM cell (fp32), n = jl*4+q so one float4 = (i,f,g,o) ----
    unsigned short* hwrite = hs_l + (size_t)(t & 1) * BB * HH;
    #pragma unroll
    for (int r = 0; r < 4; ++r) {
      int idx = r * 256 + tid;
      int m = idx >> 5, jl = idx & 31;
      float4v g4 = *(const float4v*)&gsh[m][jl * 4];
      float gi = sigm(g4[0] + bias_sh[jl * 4 + 0]);
      float gf = sigm(g4[1] + bias_sh[jl * 4 + 1]);
      float gg = tanhfast(g4[2] + bias_sh[jl * 4 + 2]);
      float go = sigm(g4[3] + bias_sh[jl * 4 + 3]);
      float c2 = gf * cst[r] + gi * gg;
      float h2 = go * tanhfast(c2);
      cst[r] = c2 * m_c[r];                       // carried c (fp32, local)
      int b = bbase + m, j = jbase + jl;
      hwrite[(size_t)b * HH + j] = f2bf(h2 * m_h[r]);   // carried h (bf16)
      if (layer == 0)
        y1ring[((size_t)(t & (Y1_DEPTH - 1)) * BB + b) * HH + j] = f2bf(h2 * m_out[r]);
      else
        out[((size_t)b * TT + t) * HH + j] = h2 * m_out[r];
    }
    __syncthreads();  // all waves' stores drained (barrier implies vmcnt(0))
    if (tid == 0) {
      __builtin_amdgcn_fence(__ATOMIC_RELEASE, "agent");
      atomicAdd(fown + t, 1);
    }
  }
}

extern "C" void kernel_launch(void* const* d_in, const int* in_sizes, int n_in,
                              void* d_out, int out_size, void* d_ws, size_t ws_size,
                              hipStream_t stream) {
  const float* x     = (const float*)d_in[0];
  const float* W_ih  = (const float*)d_in[1];
  const float* W_hh  = (const float*)d_in[2];
  const float* b_ih  = (const float*)d_in[3];
  const float* b_hh  = (const float*)d_in[4];
  const float* masks = (const float*)d_in[5];
  float* out = (float*)d_out;

  const size_t FLAG_BYTES = (size_t)2 * 4 * TT * sizeof(int);            //  32 KB
  const size_t HS_BYTES   = (size_t)2 * 2 * BB * HH * sizeof(unsigned short); // 256 KB
  const size_t Y1_BYTES   = (size_t)Y1_DEPTH * BB * HH * sizeof(unsigned short); // 1 MB
  int* flags = (int*)d_ws;
  unsigned short* hstate = (unsigned short*)((char*)d_ws + FLAG_BYTES);
  unsigned short* y1ring = (unsigned short*)((char*)d_ws + FLAG_BYTES + HS_BYTES);

  // zero flags + h init (ws is poisoned 0xAA before every launch)
  hipMemsetAsync(d_ws, 0, FLAG_BYTES + HS_BYTES + Y1_BYTES, stream);
  vlstm<<<dim3(64), dim3(256), 0, stream>>>(x, W_ih, W_hh, b_ih, b_hh, masks,
                                            out, flags, hstate, y1ring);
}